// Round 3
// baseline (376.384 us; speedup 1.0000x reference)
//
#include <hip/hip_runtime.h>
#include <hip/hip_bf16.h>

#define BB 32
#define CPD 64
#define TT 4096
#define INDIM 256
#define HH 128
#define WW 128
#define CH 64
#define WARM 32
#define NB 2
#define NCHUNK (TT/CH)

__device__ __forceinline__ float tanh_fast(float x){
    float e = __expf(2.0f*x);           // overflow -> inf -> tanh=1; underflow -> 0 -> tanh=-1
    return 1.0f - 2.0f/(e + 1.0f);
}

// K1: M[c][h] = sum_i proj[c,i] * w_ih[h,i]   (64x128, K=256)
__global__ __launch_bounds__(256) void k_proj(const float* __restrict__ proj,
                                              const float* __restrict__ w_ih,
                                              float* __restrict__ M){
    int g = blockIdx.x*256 + threadIdx.x;      // 0..8191
    int c = g >> 7, h = g & 127;
    float acc = 0.f;
    #pragma unroll 8
    for (int i = 0; i < INDIM; i += 4){
        float4 p = *(const float4*)&proj[c*INDIM + i];
        float4 q = *(const float4*)&w_ih[h*INDIM + i];
        acc = fmaf(p.x, q.x, acc);
        acc = fmaf(p.y, q.y, acc);
        acc = fmaf(p.z, q.z, acc);
        acc = fmaf(p.w, q.w, acc);
    }
    M[g] = acc;
}

// K2: xw[b][t][h] = sum_c control[b][c][t] * M[c][h]
// block: 256 threads, handles 64 t-values for one batch. grid (T/64, B)
__global__ __launch_bounds__(256) void k_xw(const float* __restrict__ control,
                                            const float* __restrict__ M,
                                            float* __restrict__ xw){
    __shared__ float ct[CPD][64];      // 16 KB   [c][t]
    __shared__ float Ml[CPD][HH];      // 32 KB
    int b  = blockIdx.y;
    int t0 = blockIdx.x * 64;
    int tid = threadIdx.x;

    #pragma unroll
    for (int k = 0; k < 32; ++k){                 // stage M (8192 elems)
        int f = tid + k*256;
        ((float*)Ml)[f] = M[f];
    }
    #pragma unroll
    for (int k = 0; k < 16; ++k){                 // stage control tile (4096 elems)
        int f = tid + k*256;
        int c = f >> 6, t = f & 63;
        ct[c][t] = control[((size_t)b*CPD + c)*TT + t0 + t];
    }
    __syncthreads();

    int h  = tid & 127;
    int tq = tid >> 7;                            // 0..1 -> 32 t's each
    float acc[32];
    #pragma unroll
    for (int j = 0; j < 32; ++j) acc[j] = 0.f;

    for (int c = 0; c < CPD; ++c){
        float mv = Ml[c][h];                      // 2-way bank alias: free
        const float* cr = &ct[c][tq*32];          // uniform: broadcast
        #pragma unroll
        for (int j = 0; j < 32; j += 4){
            float4 c4 = *(const float4*)&cr[j];
            acc[j+0] = fmaf(mv, c4.x, acc[j+0]);
            acc[j+1] = fmaf(mv, c4.y, acc[j+1]);
            acc[j+2] = fmaf(mv, c4.z, acc[j+2]);
            acc[j+3] = fmaf(mv, c4.w, acc[j+3]);
        }
    }
    #pragma unroll
    for (int j = 0; j < 32; ++j){
        int t = t0 + tq*32 + j;
        xw[((size_t)b*TT + t)*HH + h] = acc[j];   // lanes h-consecutive: coalesced
    }
}

// K3: chunked scan, split-row version. grid (NCHUNK, B/NB), block 256 (4 waves).
// Thread t: row r=t>>1, half q=t&1. Owns w_hh[r][64q..64q+63] in 64 VGPRs (pinned
// in-loop so the allocator cannot fold the loads back into the loop).
// Computes 64-wide partial dots for BOTH batches; lane pair exchanges the cross
// partial via one shfl_xor; each lane finalizes (tanh+store) batch q.
__global__ __launch_bounds__(256, 1) void k_scan(const float* __restrict__ xw,
                                                 const float* __restrict__ w_hh,
                                                 float* __restrict__ hs){
    __shared__ float hsm[2][NB][HH];
    int b0    = blockIdx.y * NB;
    int chunk = blockIdx.x;
    int tout  = chunk * CH;
    int tstart = tout - WARM; if (tstart < 0) tstart = 0;
    int tend  = tout + CH;
    int tid = threadIdx.x;
    int r = tid >> 1;
    int q = tid & 1;

    float w[64];
    #pragma unroll
    for (int j = 0; j < 64; j += 4){
        float4 w4 = *(const float4*)&w_hh[r*HH + q*64 + j];
        w[j] = w4.x; w[j+1] = w4.y; w[j+2] = w4.z; w[j+3] = w4.w;
    }

    hsm[0][q][r] = 0.f;
    __syncthreads();

    size_t basex = ((size_t)(b0+q)*TT)*HH + r;    // this thread's x/out stream
    float xn = xw[basex + (size_t)tstart*HH];
    int p = 0;                                    // read buffer
    for (int t = tstart; t < tend; ++t){
        // pin w in VGPRs: each iteration consumes the previous iteration's
        // asm outputs, so the w_hh loads cannot be re-issued inside the loop.
        #pragma unroll
        for (int j = 0; j < 64; j += 8)
            asm volatile("" : "+v"(w[j]),"+v"(w[j+1]),"+v"(w[j+2]),"+v"(w[j+3]),
                              "+v"(w[j+4]),"+v"(w[j+5]),"+v"(w[j+6]),"+v"(w[j+7]));

        float x = xn;
        int tn = (t+1 < TT) ? (t+1) : t;
        xn = xw[basex + (size_t)tn*HH];           // prefetch next step

        float p00=0.f,p01=0.f,p02=0.f,p03=0.f;    // batch 0 partial, 4 chains
        float p10=0.f,p11=0.f,p12=0.f,p13=0.f;    // batch 1 partial
        const float* h0 = &hsm[p][0][q*64];       // 2-addr broadcast reads: free
        const float* h1 = &hsm[p][1][q*64];
        #pragma unroll
        for (int j = 0; j < 64; j += 4){
            float4 a = *(const float4*)&h0[j];
            float4 c = *(const float4*)&h1[j];
            p00 = fmaf(w[j+0], a.x, p00);
            p01 = fmaf(w[j+1], a.y, p01);
            p02 = fmaf(w[j+2], a.z, p02);
            p03 = fmaf(w[j+3], a.w, p03);
            p10 = fmaf(w[j+0], c.x, p10);
            p11 = fmaf(w[j+1], c.y, p11);
            p12 = fmaf(w[j+2], c.z, p12);
            p13 = fmaf(w[j+3], c.w, p13);
        }
        float s0 = (p00+p01)+(p02+p03);
        float s1 = (p10+p11)+(p12+p13);
        float own  = q ? s1 : s0;
        float send = q ? s0 : s1;                 // partial of the batch I DON'T finalize
        float recv = __shfl_xor(send, 1, 64);     // neighbor's partial of MY batch
        float nh = tanh_fast(x + own + recv);
        hsm[p^1][q][r] = nh;                      // 2 lanes/bank: free
        __syncthreads();                          // one barrier/step (double-buffered h)
        p ^= 1;
        if (t >= tout) hs[basex + (size_t)t*HH] = nh;
    }
}

// K4: out[b][t][w] = sin( sum_k hs[b][t][k] * w_out[w][k] ), in place over the hs buffer (d_out).
// block: 256 threads, 64 t-rows. grid (T/64, B)
__global__ __launch_bounds__(256) void k_out(float* data,                      // hs in, out written in place
                                             const float* __restrict__ w_out){
    __shared__ float hsT[HH][68];      // [k][t], padded to 68 for 16B-aligned f4 reads (~35 KB)
    __shared__ float wo[WW][HH+1];     // padded 129: conflict-free spread reads (~66 KB)
    int b  = blockIdx.y;
    int t0 = blockIdx.x * 64;
    int tid = threadIdx.x;

    #pragma unroll
    for (int k = 0; k < 64; ++k){                 // stage w_out (16384 elems)
        int f = tid + k*256;
        wo[f >> 7][f & 127] = w_out[f];
    }
    size_t rowbase = ((size_t)b*TT + t0)*HH;
    #pragma unroll
    for (int k = 0; k < 32; ++k){                 // stage hs tile transposed (8192 elems)
        int f = tid + k*256;
        int t = f >> 7, kk = f & 127;
        hsT[kk][t] = data[rowbase + f];
    }
    __syncthreads();

    int w_ = tid & 127;
    int tq = tid >> 7;
    float acc[32];
    #pragma unroll
    for (int j = 0; j < 32; ++j) acc[j] = 0.f;

    for (int k = 0; k < HH; ++k){
        float wv = wo[w_][k];                     // (w_+k)%32 spread: free
        const float* hr = &hsT[k][tq*32];         // uniform: broadcast
        #pragma unroll
        for (int j = 0; j < 32; j += 4){
            float4 h4 = *(const float4*)&hr[j];
            acc[j+0] = fmaf(wv, h4.x, acc[j+0]);
            acc[j+1] = fmaf(wv, h4.y, acc[j+1]);
            acc[j+2] = fmaf(wv, h4.z, acc[j+2]);
            acc[j+3] = fmaf(wv, h4.w, acc[j+3]);
        }
    }
    #pragma unroll
    for (int j = 0; j < 32; ++j){
        int t = t0 + tq*32 + j;
        data[((size_t)b*TT + t)*WW + w_] = __sinf(acc[j]);  // coalesced over w_
    }
}

extern "C" void kernel_launch(void* const* d_in, const int* in_sizes, int n_in,
                              void* d_out, int out_size, void* d_ws, size_t ws_size,
                              hipStream_t stream) {
    const float* control = (const float*)d_in[0];
    const float* proj    = (const float*)d_in[1];
    const float* w_ih    = (const float*)d_in[2];
    const float* w_hh    = (const float*)d_in[3];
    const float* w_out   = (const float*)d_in[4];

    float* M  = (float*)d_ws;                                  // 32 KB
    float* xw = (float*)((char*)d_ws + 65536);                 // 64 MB
    float* hs = (float*)d_out;                                 // hs lives in d_out (same size)

    k_proj<<<dim3(32), dim3(256), 0, stream>>>(proj, w_ih, M);
    k_xw  <<<dim3(TT/64, BB), dim3(256), 0, stream>>>(control, M, xw);
    k_scan<<<dim3(NCHUNK, BB/NB), dim3(256), 0, stream>>>(xw, w_hh, hs);
    k_out <<<dim3(TT/64, BB), dim3(256), 0, stream>>>((float*)d_out, w_out);
}

// Round 4
// 260.515 us; speedup vs baseline: 1.4448x; 1.4448x over previous
//
#include <hip/hip_runtime.h>
#include <hip/hip_bf16.h>

#define BB 32
#define CPD 64
#define TT 4096
#define INDIM 256
#define HH 128
#define WW 128
#define CH 16
#define WARM 32
#define NS (WARM+CH)

typedef __attribute__((ext_vector_type(8))) short short8;
typedef __attribute__((ext_vector_type(4))) float f32x4;

__device__ __forceinline__ float tanh_fast(float x){
    float e = __expf(2.0f*x);           // overflow -> inf -> tanh=1; underflow -> 0 -> tanh=-1
    return 1.0f - 2.0f/(e + 1.0f);
}
// f32 -> bf16 bits, round-to-nearest-even (inputs finite here)
__device__ __forceinline__ unsigned f2bf(float f){
    unsigned u = __float_as_uint(f);
    return (u + 0x7FFFu + ((u>>16)&1u)) >> 16;
}

// K1: M[c][h] = sum_i proj[c,i] * w_ih[h,i]   (64x128, K=256)
__global__ __launch_bounds__(256) void k_proj(const float* __restrict__ proj,
                                              const float* __restrict__ w_ih,
                                              float* __restrict__ M){
    int g = blockIdx.x*256 + threadIdx.x;
    int c = g >> 7, h = g & 127;
    float acc = 0.f;
    #pragma unroll 8
    for (int i = 0; i < INDIM; i += 4){
        float4 p = *(const float4*)&proj[c*INDIM + i];
        float4 q = *(const float4*)&w_ih[h*INDIM + i];
        acc = fmaf(p.x, q.x, acc);
        acc = fmaf(p.y, q.y, acc);
        acc = fmaf(p.z, q.z, acc);
        acc = fmaf(p.w, q.w, acc);
    }
    M[g] = acc;
}

// K2: xw[b][t][h] = sum_c control[b][c][t] * M[c][h]
__global__ __launch_bounds__(256) void k_xw(const float* __restrict__ control,
                                            const float* __restrict__ M,
                                            float* __restrict__ xw){
    __shared__ float ct[CPD][64];
    __shared__ float Ml[CPD][HH];
    int b  = blockIdx.y;
    int t0 = blockIdx.x * 64;
    int tid = threadIdx.x;

    #pragma unroll
    for (int k = 0; k < 32; ++k){
        int f = tid + k*256;
        ((float*)Ml)[f] = M[f];
    }
    #pragma unroll
    for (int k = 0; k < 16; ++k){
        int f = tid + k*256;
        int c = f >> 6, t = f & 63;
        ct[c][t] = control[((size_t)b*CPD + c)*TT + t0 + t];
    }
    __syncthreads();

    int h  = tid & 127;
    int tq = tid >> 7;
    float acc[32];
    #pragma unroll
    for (int j = 0; j < 32; ++j) acc[j] = 0.f;

    for (int c = 0; c < CPD; ++c){
        float mv = Ml[c][h];
        const float* cr = &ct[c][tq*32];
        #pragma unroll
        for (int j = 0; j < 32; j += 4){
            float4 c4 = *(const float4*)&cr[j];
            acc[j+0] = fmaf(mv, c4.x, acc[j+0]);
            acc[j+1] = fmaf(mv, c4.y, acc[j+1]);
            acc[j+2] = fmaf(mv, c4.z, acc[j+2]);
            acc[j+3] = fmaf(mv, c4.w, acc[j+3]);
        }
    }
    #pragma unroll
    for (int j = 0; j < 32; ++j){
        int t = t0 + tq*32 + j;
        xw[((size_t)b*TT + t)*HH + h] = acc[j];
    }
}

// K3: MFMA chunked scan. grid(512), block 128 (2 waves).
// Streams: sigma = blockIdx*16 + (lane&15); b = sigma>>8, chunk = sigma&255.
// Step: D[i][s] = sum_j W[i][j]*H[s][j]  via mfma_f32_16x16x32_bf16,
//   A = W (stationary, bf16 frags in VGPRs, 4 N-tiles x 4 K-chunks per wave),
//   B = H (read from 4KB double-buffered LDS, granule-XOR swizzle G^s),
//   C init = xw (fp32, prefetched dwordx4, masked for t<0 warmup).
// C/D: s = lane&15 (col), i = tile*16 + (lane>>4)*4 + reg (row) -> B-frag next
// step needs only an i-bit relayout, done via conflict-free LDS bounce.
__global__ __launch_bounds__(128) void k_scan(const float* __restrict__ xw,
                                              const float* __restrict__ w_hh,
                                              float* __restrict__ hs){
    __shared__ ushort Hl[2][2048];      // [buf][s(16) x 128 bf16], XOR-swizzled granules
    const int tid  = threadIdx.x;
    const int lane = tid & 63;
    const int wv   = tid >> 6;          // wave: tiles wv*4 .. wv*4+3 (i-range 64)
    const int s    = lane & 15;         // stream slot (B-col / C-col)
    const int lg   = lane >> 4;         // lane group 0..3
    const int b     = blockIdx.x >> 4;
    const int chunk = ((blockIdx.x & 15) << 4) + s;

    // --- stationary W A-fragments: A[m=i][k=j], m=lane&15, k=lg*8+e
    short8 Wf[4][4];
    #pragma unroll
    for (int t = 0; t < 4; ++t){
        const float* wrow = &w_hh[((wv*4+t)*16 + s)*HH + lg*8];
        #pragma unroll
        for (int kc = 0; kc < 4; ++kc){
            const float* wp = wrow + kc*32;
            short8 f;
            #pragma unroll
            for (int e = 0; e < 8; ++e) f[e] = (short)f2bf(wp[e]);
            Wf[t][kc] = f;
        }
    }

    // h0 = 0
    #pragma unroll
    for (int k = 0; k < 8; ++k) ((unsigned*)Hl[0])[tid + k*128] = 0u;
    __syncthreads();

    int tg = chunk*CH - WARM;                       // may be negative (chunks 0,1)
    const float* xwp = xw + ((long long)b*TT + tg)*HH + wv*64 + lg*4;
    float*       hsp = hs + ((long long)b*TT + tg)*HH + wv*64 + lg*4;

    f32x4 xf[4];
    #pragma unroll
    for (int t = 0; t < 4; ++t) xf[t] = ((const f32x4*)xwp)[t*4];

    for (int u = 0; u < NS; ++u){
        // B-fragments of current H from LDS (conflict-free b128, swizzle G^s)
        const ushort* hb = Hl[u & 1];
        short8 Hf[4];
        #pragma unroll
        for (int kc = 0; kc < 4; ++kc){
            int G = kc*4 + lg;
            Hf[kc] = *(const short8*)&hb[s*128 + ((G ^ s)<<3)];
        }
        // C init from prefetched xw; t<0 (warmup of chunks 0,1) contributes 0
        bool ok = (tg >= 0);
        f32x4 acc[4];
        #pragma unroll
        for (int t = 0; t < 4; ++t){
            f32x4 z = {0.f,0.f,0.f,0.f};
            acc[t] = ok ? xf[t] : z;
        }
        float* hso = hsp;
        ++tg; xwp += HH; hsp += HH;
        if (u+1 < NS){                               // prefetch next step's xw
            #pragma unroll
            for (int t = 0; t < 4; ++t) xf[t] = ((const f32x4*)xwp)[t*4];
        }
        #pragma unroll
        for (int kc = 0; kc < 4; ++kc){
            #pragma unroll
            for (int t = 0; t < 4; ++t)
                acc[t] = __builtin_amdgcn_mfma_f32_16x16x32_bf16(Wf[t][kc], Hf[kc], acc[t], 0, 0, 0);
        }
        // tanh, store fp32 hs (output window), pack bf16 -> LDS for next step
        ushort* ho = Hl[(u+1) & 1];
        #pragma unroll
        for (int t = 0; t < 4; ++t){
            f32x4 a = acc[t];
            a[0] = tanh_fast(a[0]); a[1] = tanh_fast(a[1]);
            a[2] = tanh_fast(a[2]); a[3] = tanh_fast(a[3]);
            if (u >= WARM) ((f32x4*)hso)[t*4] = a;
            uint2 pk;
            pk.x = f2bf(a[0]) | (f2bf(a[1]) << 16);
            pk.y = f2bf(a[2]) | (f2bf(a[3]) << 16);
            int G = (wv*4+t)*2 + (lg>>1);
            *(uint2*)&ho[s*128 + ((G ^ s)<<3) + (lg&1)*4] = pk;   // conflict-free b64
        }
        __syncthreads();
    }
}

// K4: out[b][t][w] = sin( sum_k hs[b][t][k] * w_out[w][k] ), in place over d_out.
__global__ __launch_bounds__(256) void k_out(float* data,
                                             const float* __restrict__ w_out){
    __shared__ float hsT[HH][68];
    __shared__ float wo[WW][HH+1];
    int b  = blockIdx.y;
    int t0 = blockIdx.x * 64;
    int tid = threadIdx.x;

    #pragma unroll
    for (int k = 0; k < 64; ++k){
        int f = tid + k*256;
        wo[f >> 7][f & 127] = w_out[f];
    }
    size_t rowbase = ((size_t)b*TT + t0)*HH;
    #pragma unroll
    for (int k = 0; k < 32; ++k){
        int f = tid + k*256;
        int t = f >> 7, kk = f & 127;
        hsT[kk][t] = data[rowbase + f];
    }
    __syncthreads();

    int w_ = tid & 127;
    int tq = tid >> 7;
    float acc[32];
    #pragma unroll
    for (int j = 0; j < 32; ++j) acc[j] = 0.f;

    for (int k = 0; k < HH; ++k){
        float wv = wo[w_][k];
        const float* hr = &hsT[k][tq*32];
        #pragma unroll
        for (int j = 0; j < 32; j += 4){
            float4 h4 = *(const float4*)&hr[j];
            acc[j+0] = fmaf(wv, h4.x, acc[j+0]);
            acc[j+1] = fmaf(wv, h4.y, acc[j+1]);
            acc[j+2] = fmaf(wv, h4.z, acc[j+2]);
            acc[j+3] = fmaf(wv, h4.w, acc[j+3]);
        }
    }
    #pragma unroll
    for (int j = 0; j < 32; ++j){
        int t = t0 + tq*32 + j;
        data[((size_t)b*TT + t)*WW + w_] = __sinf(acc[j]);
    }
}

extern "C" void kernel_launch(void* const* d_in, const int* in_sizes, int n_in,
                              void* d_out, int out_size, void* d_ws, size_t ws_size,
                              hipStream_t stream) {
    const float* control = (const float*)d_in[0];
    const float* proj    = (const float*)d_in[1];
    const float* w_ih    = (const float*)d_in[2];
    const float* w_hh    = (const float*)d_in[3];
    const float* w_out   = (const float*)d_in[4];

    float* M  = (float*)d_ws;                                  // 32 KB
    float* xw = (float*)((char*)d_ws + 65536);                 // 64 MB
    float* hs = (float*)d_out;                                 // hs lives in d_out

    k_proj<<<dim3(32), dim3(256), 0, stream>>>(proj, w_ih, M);
    k_xw  <<<dim3(TT/64, BB), dim3(256), 0, stream>>>(control, M, xw);
    k_scan<<<dim3((TT/CH)*BB/16), dim3(128), 0, stream>>>(xw, w_hh, hs);
    k_out <<<dim3(TT/64, BB), dim3(256), 0, stream>>>((float*)d_out, w_out);
}

// Round 5
// 120.881 us; speedup vs baseline: 3.1137x; 2.1551x over previous
//
#include <hip/hip_runtime.h>
#include <hip/hip_bf16.h>

#define BB 32
#define CPD 64
#define TT 4096
#define INDIM 256
#define HH 128
#define WW 128
#define CH 16
#define WARM 32
#define NS (WARM+CH)

typedef __attribute__((ext_vector_type(8))) short short8;
typedef __attribute__((ext_vector_type(4))) float f32x4;

__device__ __forceinline__ float tanh_fast(float x){
    float e = __expf(2.0f*x);           // overflow -> inf -> tanh=1; underflow -> 0 -> tanh=-1
    return 1.0f - 2.0f/(e + 1.0f);
}
// f32 -> bf16 bits, round-to-nearest-even (inputs finite here)
__device__ __forceinline__ unsigned f2bf(float f){
    unsigned u = __float_as_uint(f);
    return (u + 0x7FFFu + ((u>>16)&1u)) >> 16;
}

// K1: M[c][h] = sum_i proj[c,i] * w_ih[h,i]   (64x128, K=256)
__global__ __launch_bounds__(256) void k_proj(const float* __restrict__ proj,
                                              const float* __restrict__ w_ih,
                                              float* __restrict__ M){
    int g = blockIdx.x*256 + threadIdx.x;
    int c = g >> 7, h = g & 127;
    float acc = 0.f;
    #pragma unroll 8
    for (int i = 0; i < INDIM; i += 4){
        float4 p = *(const float4*)&proj[c*INDIM + i];
        float4 q = *(const float4*)&w_ih[h*INDIM + i];
        acc = fmaf(p.x, q.x, acc);
        acc = fmaf(p.y, q.y, acc);
        acc = fmaf(p.z, q.z, acc);
        acc = fmaf(p.w, q.w, acc);
    }
    M[g] = acc;
}

// K2: xw[b][t][h] = sum_c control[b][c][t] * M[c][h]
__global__ __launch_bounds__(256) void k_xw(const float* __restrict__ control,
                                            const float* __restrict__ M,
                                            float* __restrict__ xw){
    __shared__ float ct[CPD][64];
    __shared__ float Ml[CPD][HH];
    int b  = blockIdx.y;
    int t0 = blockIdx.x * 64;
    int tid = threadIdx.x;

    #pragma unroll
    for (int k = 0; k < 32; ++k){
        int f = tid + k*256;
        ((float*)Ml)[f] = M[f];
    }
    #pragma unroll
    for (int k = 0; k < 16; ++k){
        int f = tid + k*256;
        int c = f >> 6, t = f & 63;
        ct[c][t] = control[((size_t)b*CPD + c)*TT + t0 + t];
    }
    __syncthreads();

    int h  = tid & 127;
    int tq = tid >> 7;
    float acc[32];
    #pragma unroll
    for (int j = 0; j < 32; ++j) acc[j] = 0.f;

    for (int c = 0; c < CPD; ++c){
        float mv = Ml[c][h];
        const float* cr = &ct[c][tq*32];
        #pragma unroll
        for (int j = 0; j < 32; j += 4){
            float4 c4 = *(const float4*)&cr[j];
            acc[j+0] = fmaf(mv, c4.x, acc[j+0]);
            acc[j+1] = fmaf(mv, c4.y, acc[j+1]);
            acc[j+2] = fmaf(mv, c4.z, acc[j+2]);
            acc[j+3] = fmaf(mv, c4.w, acc[j+3]);
        }
    }
    #pragma unroll
    for (int j = 0; j < 32; ++j){
        int t = t0 + tq*32 + j;
        xw[((size_t)b*TT + t)*HH + h] = acc[j];
    }
}

// K3: MFMA chunked scan WITH FUSED OUTPUT PROJECTION + sin.
// grid(512), block 128 (2 waves). Streams: sigma = blockIdx*16 + (lane&15).
// Recurrence: D[i][s] = sum_j W[i][j]*H[s][j] via mfma_f32_16x16x32_bf16
//   (A = W_hh stationary frags, B = H from 4KB double-buffered swizzled LDS,
//    C init = xw fp32).
// Fused out: at iter u, Hf = H(tg-1); for tg-1 >= tout compute
//   out[w][s] = sum_k w_out[w][k]*H[s][k] with A = w_out stationary frags and
//   the SAME Hf operands, then sin + store fp32 to d_out. Epilogue does the
//   final time step. These MFMAs are independent of the recurrence chain ->
//   they fill the matrix pipe during tanh/LDS latency.
__global__ __launch_bounds__(128, 1) void k_scan(const float* __restrict__ xw,
                                                 const float* __restrict__ w_hh,
                                                 const float* __restrict__ w_out,
                                                 float* __restrict__ out){
    __shared__ ushort Hl[2][2048];      // [buf][s(16) x 128 bf16], XOR-swizzled granules
    const int tid  = threadIdx.x;
    const int lane = tid & 63;
    const int wv   = tid >> 6;          // wave: i/w rows wv*64 .. wv*64+63
    const int s    = lane & 15;         // stream slot (B-col / C-col)
    const int lg   = lane >> 4;         // lane group 0..3
    const int b     = blockIdx.x >> 4;
    const int chunk = ((blockIdx.x & 15) << 4) + s;

    // stationary A-fragments: A[m][k], m=lane&15, k=lg*8+e (+kc*32)
    short8 Wf[4][4];                    // w_hh rows (recurrence)
    short8 Wo[4][4];                    // w_out rows (output projection)
    #pragma unroll
    for (int t = 0; t < 4; ++t){
        const float* wrow = &w_hh [((wv*4+t)*16 + s)*HH + lg*8];
        const float* orow = &w_out[((wv*4+t)*16 + s)*HH + lg*8];
        #pragma unroll
        for (int kc = 0; kc < 4; ++kc){
            short8 f, g;
            #pragma unroll
            for (int e = 0; e < 8; ++e){ f[e] = (short)f2bf(wrow[kc*32+e]);
                                         g[e] = (short)f2bf(orow[kc*32+e]); }
            Wf[t][kc] = f;
            Wo[t][kc] = g;
        }
    }

    // h0 = 0
    #pragma unroll
    for (int k = 0; k < 8; ++k) ((unsigned*)Hl[0])[tid + k*128] = 0u;
    __syncthreads();

    int tg = chunk*CH - WARM;                       // may be negative (chunks 0,1)
    const float* xwp  = xw  + ((long long)b*TT + tg)*HH + wv*64 + lg*4;
    float*       outp = out + ((long long)b*TT + tg)*HH + wv*64 + lg*4;

    f32x4 xf[4];
    #pragma unroll
    for (int t = 0; t < 4; ++t) xf[t] = ((const f32x4*)xwp)[t*4];

    for (int u = 0; u < NS; ++u){
        // B-fragments of current H from LDS (conflict-free b128, swizzle G^s)
        const ushort* hb = Hl[u & 1];
        short8 Hf[4];
        #pragma unroll
        for (int kc = 0; kc < 4; ++kc){
            int G = kc*4 + lg;
            Hf[kc] = *(const short8*)&hb[s*128 + ((G ^ s)<<3)];
        }

        // ---- fused out-projection for time tg-1 (H(tg-1) == Hf) ----
        if (u > WARM){
            f32x4 o[4];
            #pragma unroll
            for (int t = 0; t < 4; ++t){ f32x4 z = {0.f,0.f,0.f,0.f}; o[t] = z; }
            #pragma unroll
            for (int kc = 0; kc < 4; ++kc){
                #pragma unroll
                for (int t = 0; t < 4; ++t)
                    o[t] = __builtin_amdgcn_mfma_f32_16x16x32_bf16(Wo[t][kc], Hf[kc], o[t], 0, 0, 0);
            }
            float* op = outp - HH;
            #pragma unroll
            for (int t = 0; t < 4; ++t){
                f32x4 a = o[t];
                a[0] = __sinf(a[0]); a[1] = __sinf(a[1]);
                a[2] = __sinf(a[2]); a[3] = __sinf(a[3]);
                ((f32x4*)op)[t*4] = a;
            }
        }

        // ---- recurrence step: H(tg) = tanh(xw(tg) + W*H(tg-1)) ----
        bool ok = (tg >= 0);
        f32x4 acc[4];
        #pragma unroll
        for (int t = 0; t < 4; ++t){
            f32x4 z = {0.f,0.f,0.f,0.f};
            acc[t] = ok ? xf[t] : z;
        }
        ++tg; xwp += HH; outp += HH;
        if (u+1 < NS){                               // prefetch next step's xw
            #pragma unroll
            for (int t = 0; t < 4; ++t) xf[t] = ((const f32x4*)xwp)[t*4];
        }
        #pragma unroll
        for (int kc = 0; kc < 4; ++kc){
            #pragma unroll
            for (int t = 0; t < 4; ++t)
                acc[t] = __builtin_amdgcn_mfma_f32_16x16x32_bf16(Wf[t][kc], Hf[kc], acc[t], 0, 0, 0);
        }
        // tanh, pack bf16 -> LDS for next step
        ushort* ho = Hl[(u+1) & 1];
        #pragma unroll
        for (int t = 0; t < 4; ++t){
            f32x4 a = acc[t];
            a[0] = tanh_fast(a[0]); a[1] = tanh_fast(a[1]);
            a[2] = tanh_fast(a[2]); a[3] = tanh_fast(a[3]);
            uint2 pk;
            pk.x = f2bf(a[0]) | (f2bf(a[1]) << 16);
            pk.y = f2bf(a[2]) | (f2bf(a[3]) << 16);
            int G = (wv*4+t)*2 + (lg>>1);
            *(uint2*)&ho[s*128 + ((G ^ s)<<3) + (lg&1)*4] = pk;   // conflict-free b64
        }
        __syncthreads();
    }

    // ---- epilogue: out for the final time step (tout+CH-1) ----
    {
        const ushort* hb = Hl[NS & 1];
        short8 Hf[4];
        #pragma unroll
        for (int kc = 0; kc < 4; ++kc){
            int G = kc*4 + lg;
            Hf[kc] = *(const short8*)&hb[s*128 + ((G ^ s)<<3)];
        }
        f32x4 o[4];
        #pragma unroll
        for (int t = 0; t < 4; ++t){ f32x4 z = {0.f,0.f,0.f,0.f}; o[t] = z; }
        #pragma unroll
        for (int kc = 0; kc < 4; ++kc){
            #pragma unroll
            for (int t = 0; t < 4; ++t)
                o[t] = __builtin_amdgcn_mfma_f32_16x16x32_bf16(Wo[t][kc], Hf[kc], o[t], 0, 0, 0);
        }
        float* op = outp - HH;
        #pragma unroll
        for (int t = 0; t < 4; ++t){
            f32x4 a = o[t];
            a[0] = __sinf(a[0]); a[1] = __sinf(a[1]);
            a[2] = __sinf(a[2]); a[3] = __sinf(a[3]);
            ((f32x4*)op)[t*4] = a;
        }
    }
}

extern "C" void kernel_launch(void* const* d_in, const int* in_sizes, int n_in,
                              void* d_out, int out_size, void* d_ws, size_t ws_size,
                              hipStream_t stream) {
    const float* control = (const float*)d_in[0];
    const float* proj    = (const float*)d_in[1];
    const float* w_ih    = (const float*)d_in[2];
    const float* w_hh    = (const float*)d_in[3];
    const float* w_out   = (const float*)d_in[4];

    float* M  = (float*)d_ws;                                  // 32 KB
    float* xw = (float*)((char*)d_ws + 65536);                 // 64 MB

    k_proj<<<dim3(32), dim3(256), 0, stream>>>(proj, w_ih, M);
    k_xw  <<<dim3(TT/64, BB), dim3(256), 0, stream>>>(control, M, xw);
    k_scan<<<dim3((TT/CH)*BB/16), dim3(128), 0, stream>>>(xw, w_hh, w_out, (float*)d_out);
}